// Round 3
// baseline (160.886 us; speedup 1.0000x reference)
//
#include <hip/hip_runtime.h>

// TokenSelector: out[b,h,q,s,:] = kv[b,h,indices[b,h,q,s],:]
// Shapes: kv (2,16,4096,128) f32, indices (2,16,512,64) int32, out (2,16,512,64,128) f32.
// Pure gather, memory-bound: 537 MB written, kv (64 MiB) mostly cache-resident.
// R2: native ext_vector f32x4 (nontemporal builtin rejects HIP float4 class),
//     4-way independent unroll (MLP) + nontemporal out stores (don't thrash L2).

namespace {
typedef float f32x4 __attribute__((ext_vector_type(4)));

constexpr long long T_Q = 512;
constexpr long long N_SEL = 64;
constexpr long long TOTAL_VEC = 2LL * 16 * T_Q * N_SEL * 32;  // 33,554,432 f32x4
// row -> bh: row >> 15 ; kv row base (in f32x4 units): ((bh<<12) + r) << 5

__device__ __forceinline__ long long src_vec(const int* __restrict__ idx, long long t) {
    const long long row = t >> 5;
    const long long bh = row >> 15;
    const int r = idx[row];
    return ((bh << 12) + (long long)r) * 32 + (t & 31);
}

__global__ void token_selector_gather(const f32x4* __restrict__ kv,
                                      const int* __restrict__ idx,
                                      f32x4* __restrict__ out) {
    const long long t0 = (long long)blockIdx.x * blockDim.x + threadIdx.x;
    const long long stride = (long long)gridDim.x * blockDim.x;

    long long t = t0;
    // 4 independent gather chains per iteration -> 4x memory-level parallelism.
    for (; t + 3 * stride < TOTAL_VEC; t += 4 * stride) {
        const long long sa = src_vec(idx, t);
        const long long sb = src_vec(idx, t + stride);
        const long long sc = src_vec(idx, t + 2 * stride);
        const long long sd = src_vec(idx, t + 3 * stride);
        const f32x4 va = kv[sa];
        const f32x4 vb = kv[sb];
        const f32x4 vc = kv[sc];
        const f32x4 vd = kv[sd];
        __builtin_nontemporal_store(va, &out[t]);
        __builtin_nontemporal_store(vb, &out[t + stride]);
        __builtin_nontemporal_store(vc, &out[t + 2 * stride]);
        __builtin_nontemporal_store(vd, &out[t + 3 * stride]);
    }
    for (; t < TOTAL_VEC; t += stride) {
        const f32x4 v = kv[src_vec(idx, t)];
        __builtin_nontemporal_store(v, &out[t]);
    }
}
} // namespace

extern "C" void kernel_launch(void* const* d_in, const int* in_sizes, int n_in,
                              void* d_out, int out_size, void* d_ws, size_t ws_size,
                              hipStream_t stream) {
    const f32x4* kv = (const f32x4*)d_in[0];
    const int* idx = (const int*)d_in[1];
    f32x4* out = (f32x4*)d_out;

    const int block = 256;
    const int grid = 2048;  // 524288 threads; 64 vec/thread; unroll-4 divides exactly
    token_selector_gather<<<grid, block, 0, stream>>>(kv, idx, out);
}

// Round 4
// 119.405 us; speedup vs baseline: 1.3474x; 1.3474x over previous
//
#include <hip/hip_runtime.h>

// TokenSelector: out[b,h,q,s,:] = kv[b,h,indices[b,h,q,s],:]
// kv (2,16,4096,128) f32, indices (2,16,512,64) int32, out (2,16,512,64,128) f32.
// R3: XCD-aware bh partitioning. Each XCD (blockIdx%8) owns 4 bh slices and
// sweeps them sequentially; its 2 MiB kv slice stays resident in that XCD's
// 4 MiB L2 and is fetched from HBM once (vs 8x-duplicated x 32 phases before).
// nt stores keep the 537 MB write stream from evicting the slice.

namespace {
typedef float f32x4 __attribute__((ext_vector_type(4)));

constexpr int NXCD = 8;
constexpr int BH = 32;                      // B*H
constexpr int BH_PER_XCD = BH / NXCD;       // 4
constexpr long long W_BH = 32768LL * 32;    // f32x4 per bh slice = 1,048,576

__global__ void token_selector_gather(const f32x4* __restrict__ kv,
                                      const int* __restrict__ idx,
                                      f32x4* __restrict__ out) {
    const int xcd = blockIdx.x & (NXCD - 1);          // physical XCD (round-robin)
    const int xblk = blockIdx.x / NXCD;               // block index within XCD
    const long long tix = (long long)xblk * blockDim.x + threadIdx.x;
    const long long xthreads = (long long)(gridDim.x / NXCD) * blockDim.x; // 65536

    for (int pb = 0; pb < BH_PER_XCD; ++pb) {
        const long long bh = (long long)xcd * BH_PER_XCD + pb;
        const long long out_base = bh * W_BH;
        const long long row_base = bh << 15;          // 32768 rows per bh
        const long long kv_base = bh << 17;           // bh * 4096 * 32 (f32x4)

        long long i = tix;
        // W_BH / xthreads = 16 iterations -> 4 macro-iters of unroll-4, no tail.
        for (; i + 3 * xthreads < W_BH; i += 4 * xthreads) {
            const long long ia = i;
            const long long ib = i + xthreads;
            const long long ic = i + 2 * xthreads;
            const long long id = i + 3 * xthreads;
            const int ra = idx[row_base + (ia >> 5)];
            const int rb = idx[row_base + (ib >> 5)];
            const int rc = idx[row_base + (ic >> 5)];
            const int rd = idx[row_base + (id >> 5)];
            const f32x4 va = kv[kv_base + ((long long)ra << 5) + (ia & 31)];
            const f32x4 vb = kv[kv_base + ((long long)rb << 5) + (ib & 31)];
            const f32x4 vc = kv[kv_base + ((long long)rc << 5) + (ic & 31)];
            const f32x4 vd = kv[kv_base + ((long long)rd << 5) + (id & 31)];
            __builtin_nontemporal_store(va, &out[out_base + ia]);
            __builtin_nontemporal_store(vb, &out[out_base + ib]);
            __builtin_nontemporal_store(vc, &out[out_base + ic]);
            __builtin_nontemporal_store(vd, &out[out_base + id]);
        }
        for (; i < W_BH; i += xthreads) {
            const int r = idx[row_base + (i >> 5)];
            const f32x4 v = kv[kv_base + ((long long)r << 5) + (i & 31)];
            __builtin_nontemporal_store(v, &out[out_base + i]);
        }
    }
}
} // namespace

extern "C" void kernel_launch(void* const* d_in, const int* in_sizes, int n_in,
                              void* d_out, int out_size, void* d_ws, size_t ws_size,
                              hipStream_t stream) {
    const f32x4* kv = (const f32x4*)d_in[0];
    const int* idx = (const int*)d_in[1];
    f32x4* out = (f32x4*)d_out;

    const int block = 256;
    const int grid = 2048;  // 256 blocks per XCD; fully resident (8 blk/CU)
    token_selector_gather<<<grid, block, 0, stream>>>(kv, idx, out);
}